// Round 1
// baseline (270.551 us; speedup 1.0000x reference)
//
#include <hip/hip_runtime.h>
#include <hip/hip_bf16.h>

#define D 128           // D_IN == D_OUT == 128
#define GEMM_ROWS 32    // rows of x per block in the GEMM

// ---------------------------------------------------------------------------
// Kernel 1: h = x @ w   (fp32, vector ALU — no fp32 MFMA on CDNA4)
// Block: 256 threads. Tile: 32 rows x 128 cols. Per-thread 4x4 register tile.
// w (64 KB) and the 32x128 x-tile (16 KB) staged in LDS -> 80 KB, 2 blocks/CU.
// ---------------------------------------------------------------------------
__global__ __launch_bounds__(256) void gemm128(const float* __restrict__ x,
                                               const float* __restrict__ w,
                                               float* __restrict__ h, int n) {
    __shared__ float4 ws4[D * D / 4];     // 64 KB, w row-major as float4
    __shared__ float  xs[GEMM_ROWS][D];   // 16 KB

    const int tid  = threadIdx.x;
    const int row0 = blockIdx.x * GEMM_ROWS;

    // stage w: 4096 float4, 16 per thread, coalesced
    const float4* w4 = (const float4*)w;
    for (int i = tid; i < D * D / 4; i += 256) ws4[i] = w4[i];

    // stage x tile: 1024 float4, guard the ragged last block
    float4* xs4 = (float4*)&xs[0][0];
    const float4* x4 = (const float4*)x;
    for (int i = tid; i < GEMM_ROWS * D / 4; i += 256) {
        int row = row0 + (i >> 5);                 // i / (D/4)
        float4 v = make_float4(0.f, 0.f, 0.f, 0.f);
        if (row < n) v = x4[(size_t)row0 * (D / 4) + i];
        xs4[i] = v;
    }
    __syncthreads();

    const int tx = tid & 31;   // column quad: cols [4*tx, 4*tx+3]
    const int ty = tid >> 5;   // row group (8 groups x 4 rows = 32 rows)

    float4 acc[4];
#pragma unroll
    for (int i = 0; i < 4; ++i) acc[i] = make_float4(0.f, 0.f, 0.f, 0.f);

#pragma unroll 8
    for (int k = 0; k < D; ++k) {
        float4 wv = ws4[k * (D / 4) + tx];   // b128, conflict-free across tx
#pragma unroll
        for (int i = 0; i < 4; ++i) {
            float xv = xs[ty * 4 + i][k];    // 2-addr broadcast per wave (free)
            acc[i].x = fmaf(xv, wv.x, acc[i].x);
            acc[i].y = fmaf(xv, wv.y, acc[i].y);
            acc[i].z = fmaf(xv, wv.z, acc[i].z);
            acc[i].w = fmaf(xv, wv.w, acc[i].w);
        }
    }

#pragma unroll
    for (int i = 0; i < 4; ++i) {
        int row = row0 + ty * 4 + i;
        if (row < n) ((float4*)(h + (size_t)row * D))[tx] = acc[i];
    }
}

// ---------------------------------------------------------------------------
// Kernel 2: out[r] = relu( sum_{e: rows[e]==r} vals[e] * h[cols[e]] )
// adj_rows is SORTED -> one block per output row, binary-search the edge
// range. No atomics, no zero-init, ReLU fused into the single store.
// Block: 128 threads, thread d owns output dim d (coalesced 512B gathers).
// ---------------------------------------------------------------------------
__global__ __launch_bounds__(128) void spmm_row(const float* __restrict__ h,
                                                const int* __restrict__ rows,
                                                const int* __restrict__ cols,
                                                const float* __restrict__ vals,
                                                float* __restrict__ out,
                                                int n_edges) {
    const int r = blockIdx.x;
    const int d = threadIdx.x;

    // lower_bound(rows, r)  — uniform across the block -> scalar loads
    int lo = 0, hi = n_edges;
    while (lo < hi) {
        int mid = (lo + hi) >> 1;
        if (rows[mid] < r) lo = mid + 1; else hi = mid;
    }
    const int start = lo;
    // upper_bound(rows, r)
    hi = n_edges;
    while (lo < hi) {
        int mid = (lo + hi) >> 1;
        if (rows[mid] <= r) lo = mid + 1; else hi = mid;
    }
    const int end = lo;

    float acc = 0.f;
    for (int e = start; e < end; ++e) {
        int   c = cols[e];    // uniform -> scalar load
        float v = vals[e];    // uniform -> scalar load
        acc = fmaf(v, h[(size_t)c * D + d], acc);   // coalesced 512B gather
    }
    out[(size_t)r * D + d] = fmaxf(acc, 0.f);
}

// ---------------------------------------------------------------------------
// Fallback (only if ws_size can't hold h): recompute h[c] per edge. Slow but
// correct; expected never to run (needs 25.6 MB of workspace).
// ---------------------------------------------------------------------------
__global__ __launch_bounds__(128) void fused_fallback(
        const float* __restrict__ x, const float* __restrict__ w,
        const int* __restrict__ rows, const int* __restrict__ cols,
        const float* __restrict__ vals, float* __restrict__ out, int n_edges) {
    const int r = blockIdx.x;
    const int d = threadIdx.x;

    int lo = 0, hi = n_edges;
    while (lo < hi) { int m = (lo + hi) >> 1; if (rows[m] < r) lo = m + 1; else hi = m; }
    const int start = lo;
    hi = n_edges;
    while (lo < hi) { int m = (lo + hi) >> 1; if (rows[m] <= r) lo = m + 1; else hi = m; }
    const int end = lo;

    float acc = 0.f;
    for (int e = start; e < end; ++e) {
        int c = cols[e]; float v = vals[e];
        float hcd = 0.f;
        for (int k = 0; k < D; ++k)
            hcd = fmaf(x[(size_t)c * D + k], w[(size_t)k * D + d], hcd);
        acc = fmaf(v, hcd, acc);
    }
    out[(size_t)r * D + d] = fmaxf(acc, 0.f);
}

extern "C" void kernel_launch(void* const* d_in, const int* in_sizes, int n_in,
                              void* d_out, int out_size, void* d_ws, size_t ws_size,
                              hipStream_t stream) {
    const float* x    = (const float*)d_in[0];
    const float* w    = (const float*)d_in[1];
    const int*   rows = (const int*)d_in[2];
    const int*   cols = (const int*)d_in[3];
    const float* vals = (const float*)d_in[4];
    float* out = (float*)d_out;

    const int n_nodes = in_sizes[0] / D;   // 50000
    const int n_edges = in_sizes[2];       // 800000

    const size_t h_bytes = (size_t)n_nodes * D * sizeof(float);  // 25.6 MB
    if (ws_size >= h_bytes) {
        float* h = (float*)d_ws;
        const int gemm_blocks = (n_nodes + GEMM_ROWS - 1) / GEMM_ROWS;
        gemm128<<<gemm_blocks, 256, 0, stream>>>(x, w, h, n_nodes);
        spmm_row<<<n_nodes, 128, 0, stream>>>(h, rows, cols, vals, out, n_edges);
    } else {
        fused_fallback<<<n_nodes, 128, 0, stream>>>(x, w, rows, cols, vals, out, n_edges);
    }
}

// Round 2
// 160.237 us; speedup vs baseline: 1.6884x; 1.6884x over previous
//
#include <hip/hip_runtime.h>
#include <hip/hip_bf16.h>

#define D 128           // D_IN == D_OUT == 128
#define GEMM_ROWS 32

typedef __bf16 bf16x8 __attribute__((ext_vector_type(8)));
typedef float  f32x4  __attribute__((ext_vector_type(4)));
typedef unsigned int u32x4 __attribute__((ext_vector_type(4)));

// ---------------------------------------------------------------------------
// Pre-kernel A: wT[n][k] = bf16(w[k][n]).  16384 elements, trivial.
// ---------------------------------------------------------------------------
__global__ void transpose_w(const float* __restrict__ w, unsigned short* __restrict__ wT) {
    int idx = blockIdx.x * 256 + threadIdx.x;      // coalesced read of w
    float v = w[idx];
    int k = idx >> 7, c = idx & 127;
    wT[c * D + k] = __builtin_bit_cast(unsigned short, (__bf16)v);
}

// ---------------------------------------------------------------------------
// Pre-kernel B: CSR row_ptr from sorted COO rows (scatter at run boundaries).
// row_ptr[r] = first edge with rows[e] >= r;  row_ptr[n_nodes] = n_edges.
// ---------------------------------------------------------------------------
__global__ void build_row_ptr(const int* __restrict__ rows, int* __restrict__ row_ptr,
                              int n_edges, int n_nodes) {
    int e = blockIdx.x * 256 + threadIdx.x;
    if (e >= n_edges) return;
    int r    = rows[e];
    int prev = (e == 0) ? -1 : rows[e - 1];
    for (int rr = prev + 1; rr <= r; ++rr) row_ptr[rr] = e;
    if (e == n_edges - 1)
        for (int rr = r + 1; rr <= n_nodes; ++rr) row_ptr[rr] = n_edges;
}

// ---------------------------------------------------------------------------
// GEMM: h = x @ w via 16x16x32 bf16 MFMA. NO LDS (r1 fp32 version was
// LDS-throughput bound). A: global fp32 -> in-register bf16 (layout
// A[m=lane&15][k=(lane>>4)*8+j] -> 2 contiguous float4 loads). B: 16B loads
// from L2-resident wT[n][k]. Wave = 32 rows (2 slabs of 16) x 128 cols.
// ---------------------------------------------------------------------------
__device__ inline bf16x8 load_a_frag(const float* __restrict__ x, int r, int koff, int n) {
    float4 v0 = make_float4(0.f, 0.f, 0.f, 0.f), v1 = v0;
    if (r < n) {
        const float4* p = (const float4*)(x + (size_t)r * D + koff);
        v0 = p[0]; v1 = p[1];
    }
    bf16x8 a;
    a[0] = (__bf16)v0.x; a[1] = (__bf16)v0.y; a[2] = (__bf16)v0.z; a[3] = (__bf16)v0.w;
    a[4] = (__bf16)v1.x; a[5] = (__bf16)v1.y; a[6] = (__bf16)v1.z; a[7] = (__bf16)v1.w;
    return a;
}

__global__ __launch_bounds__(256) void gemm_mfma(const float* __restrict__ x,
                                                 const unsigned short* __restrict__ wT,
                                                 float* __restrict__ h, int n) {
    const int wave = threadIdx.x >> 6;
    const int lane = threadIdx.x & 63;
    const int m16  = lane & 15;     // A row in tile / B col / D col
    const int q    = lane >> 4;     // k-quad for A/B; row-quad for D

    const int row_base = (blockIdx.x * 4 + wave) * 32;   // 32 rows per wave
    const int r0 = row_base + m16;
    const int r1 = row_base + 16 + m16;

    f32x4 acc0[8], acc1[8];
#pragma unroll
    for (int t = 0; t < 8; ++t) { acc0[t] = (f32x4)0.f; acc1[t] = (f32x4)0.f; }

    const u32x4* wTv = (const u32x4*)wT;

#pragma unroll
    for (int s = 0; s < 4; ++s) {                 // K chunks of 32
        const int koff = 32 * s + q * 8;          // this lane's 8 k's
        bf16x8 a0 = load_a_frag(x, r0, koff, n);
        bf16x8 a1 = load_a_frag(x, r1, koff, n);
#pragma unroll
        for (int t = 0; t < 8; ++t) {             // 8 col-tiles of 16
            int ncol = 16 * t + m16;
            bf16x8 b = __builtin_bit_cast(bf16x8, wTv[(ncol * D + koff) >> 3]);
            acc0[t] = __builtin_amdgcn_mfma_f32_16x16x32_bf16(a0, b, acc0[t], 0, 0, 0);
            acc1[t] = __builtin_amdgcn_mfma_f32_16x16x32_bf16(a1, b, acc1[t], 0, 0, 0);
        }
    }

    // D layout: col = lane&15, row = (lane>>4)*4 + i   [m89-verified]
#pragma unroll
    for (int t = 0; t < 8; ++t) {
        int col = 16 * t + m16;
#pragma unroll
        for (int i = 0; i < 4; ++i) {
            int rr0 = row_base + q * 4 + i;
            if (rr0 < n) h[(size_t)rr0 * D + col] = acc0[t][i];
            int rr1 = row_base + 16 + q * 4 + i;
            if (rr1 < n) h[(size_t)rr1 * D + col] = acc1[t][i];
        }
    }
}

// ---------------------------------------------------------------------------
// SpMM: one wave per row via row_ptr (2 loads vs 40-load binary search).
// Two half-wave float4 gather chains (32 lanes x 16B = full h row), software
// prefetch of next col/val so the index load overlaps the current gather.
// ---------------------------------------------------------------------------
__global__ __launch_bounds__(256) void spmm_csr(const float* __restrict__ h,
                                                const int* __restrict__ row_ptr,
                                                const int* __restrict__ cols,
                                                const float* __restrict__ vals,
                                                float* __restrict__ out, int n) {
    const int wave = threadIdx.x >> 6;
    const int lane = threadIdx.x & 63;
    const int r = blockIdx.x * 4 + wave;
    if (r >= n) return;

    const int start = row_ptr[r];
    const int end   = row_ptr[r + 1];
    const int eh = lane >> 5;       // which edge chain (0/1)
    const int l4 = lane & 31;       // float4 slot within the row

    const float4* h4 = (const float4*)h;
    float4 acc = make_float4(0.f, 0.f, 0.f, 0.f);

    int e = start + eh;
    int c = 0; float v = 0.f;
    if (e < end) { c = cols[e]; v = vals[e]; }
    while (e < end) {
        int en = e + 2; int cn = 0; float vn = 0.f;
        if (en < end) { cn = cols[en]; vn = vals[en]; }   // overlaps gather below
        float4 hv = h4[(size_t)c * (D / 4) + l4];
        acc.x = fmaf(v, hv.x, acc.x);
        acc.y = fmaf(v, hv.y, acc.y);
        acc.z = fmaf(v, hv.z, acc.z);
        acc.w = fmaf(v, hv.w, acc.w);
        c = cn; v = vn; e = en;
    }

    // combine the two half-wave chains
    acc.x += __shfl_xor(acc.x, 32);
    acc.y += __shfl_xor(acc.y, 32);
    acc.z += __shfl_xor(acc.z, 32);
    acc.w += __shfl_xor(acc.w, 32);

    if (eh == 0) {
        float4 o;
        o.x = fmaxf(acc.x, 0.f); o.y = fmaxf(acc.y, 0.f);
        o.z = fmaxf(acc.z, 0.f); o.w = fmaxf(acc.w, 0.f);
        ((float4*)out)[(size_t)r * (D / 4) + l4] = o;
    }
}

// ============================ fallback tier ================================
__global__ __launch_bounds__(256) void gemm128(const float* __restrict__ x,
                                               const float* __restrict__ w,
                                               float* __restrict__ h, int n) {
    __shared__ float4 ws4[D * D / 4];
    __shared__ float  xs[GEMM_ROWS][D];
    const int tid  = threadIdx.x;
    const int row0 = blockIdx.x * GEMM_ROWS;
    const float4* w4 = (const float4*)w;
    for (int i = tid; i < D * D / 4; i += 256) ws4[i] = w4[i];
    float4* xs4 = (float4*)&xs[0][0];
    const float4* x4 = (const float4*)x;
    for (int i = tid; i < GEMM_ROWS * D / 4; i += 256) {
        int row = row0 + (i >> 5);
        float4 v = make_float4(0.f, 0.f, 0.f, 0.f);
        if (row < n) v = x4[(size_t)row0 * (D / 4) + i];
        xs4[i] = v;
    }
    __syncthreads();
    const int tx = tid & 31, ty = tid >> 5;
    float4 acc[4];
#pragma unroll
    for (int i = 0; i < 4; ++i) acc[i] = make_float4(0.f, 0.f, 0.f, 0.f);
#pragma unroll 8
    for (int k = 0; k < D; ++k) {
        float4 wv = ws4[k * (D / 4) + tx];
#pragma unroll
        for (int i = 0; i < 4; ++i) {
            float xv = xs[ty * 4 + i][k];
            acc[i].x = fmaf(xv, wv.x, acc[i].x);
            acc[i].y = fmaf(xv, wv.y, acc[i].y);
            acc[i].z = fmaf(xv, wv.z, acc[i].z);
            acc[i].w = fmaf(xv, wv.w, acc[i].w);
        }
    }
#pragma unroll
    for (int i = 0; i < 4; ++i) {
        int row = row0 + ty * 4 + i;
        if (row < n) ((float4*)(h + (size_t)row * D))[tx] = acc[i];
    }
}

__global__ __launch_bounds__(128) void spmm_row(const float* __restrict__ h,
                                                const int* __restrict__ rows,
                                                const int* __restrict__ cols,
                                                const float* __restrict__ vals,
                                                float* __restrict__ out, int n_edges) {
    const int r = blockIdx.x, d = threadIdx.x;
    int lo = 0, hi = n_edges;
    while (lo < hi) { int m = (lo + hi) >> 1; if (rows[m] < r) lo = m + 1; else hi = m; }
    const int start = lo;
    hi = n_edges;
    while (lo < hi) { int m = (lo + hi) >> 1; if (rows[m] <= r) lo = m + 1; else hi = m; }
    const int end = lo;
    float acc = 0.f;
    for (int e = start; e < end; ++e)
        acc = fmaf(vals[e], h[(size_t)cols[e] * D + d], acc);
    out[(size_t)r * D + d] = fmaxf(acc, 0.f);
}

__global__ __launch_bounds__(128) void fused_fallback(
        const float* __restrict__ x, const float* __restrict__ w,
        const int* __restrict__ rows, const int* __restrict__ cols,
        const float* __restrict__ vals, float* __restrict__ out, int n_edges) {
    const int r = blockIdx.x, d = threadIdx.x;
    int lo = 0, hi = n_edges;
    while (lo < hi) { int m = (lo + hi) >> 1; if (rows[m] < r) lo = m + 1; else hi = m; }
    const int start = lo;
    hi = n_edges;
    while (lo < hi) { int m = (lo + hi) >> 1; if (rows[m] <= r) lo = m + 1; else hi = m; }
    const int end = lo;
    float acc = 0.f;
    for (int e = start; e < end; ++e) {
        int c = cols[e]; float v = vals[e];
        float hcd = 0.f;
        for (int k = 0; k < D; ++k)
            hcd = fmaf(x[(size_t)c * D + k], w[(size_t)k * D + d], hcd);
        acc = fmaf(v, hcd, acc);
    }
    out[(size_t)r * D + d] = fmaxf(acc, 0.f);
}

// ===========================================================================
extern "C" void kernel_launch(void* const* d_in, const int* in_sizes, int n_in,
                              void* d_out, int out_size, void* d_ws, size_t ws_size,
                              hipStream_t stream) {
    const float* x    = (const float*)d_in[0];
    const float* w    = (const float*)d_in[1];
    const int*   rows = (const int*)d_in[2];
    const int*   cols = (const int*)d_in[3];
    const float* vals = (const float*)d_in[4];
    float* out = (float*)d_out;

    const int n_nodes = in_sizes[0] / D;   // 50000
    const int n_edges = in_sizes[2];       // 800000

    const size_t h_bytes  = (size_t)n_nodes * D * sizeof(float);     // 25.6 MB
    const size_t wT_off   = h_bytes;                                 // 16B-aligned
    const size_t rp_off   = wT_off + (size_t)D * D * sizeof(unsigned short);
    const size_t need     = rp_off + (size_t)(n_nodes + 1) * sizeof(int);

    if (ws_size >= need) {
        float*          h  = (float*)d_ws;
        unsigned short* wT = (unsigned short*)((char*)d_ws + wT_off);
        int*            rp = (int*)((char*)d_ws + rp_off);

        transpose_w<<<(D * D) / 256, 256, 0, stream>>>(w, wT);
        build_row_ptr<<<(n_edges + 255) / 256, 256, 0, stream>>>(rows, rp, n_edges, n_nodes);

        const int rows_per_block = 128;    // 4 waves x 32 rows
        gemm_mfma<<<(n_nodes + rows_per_block - 1) / rows_per_block, 256, 0, stream>>>(x, wT, h, n_nodes);
        spmm_csr<<<(n_nodes + 3) / 4, 256, 0, stream>>>(h, rp, cols, vals, out, n_nodes);
    } else if (ws_size >= h_bytes) {
        float* h = (float*)d_ws;
        gemm128<<<(n_nodes + GEMM_ROWS - 1) / GEMM_ROWS, 256, 0, stream>>>(x, w, h, n_nodes);
        spmm_row<<<n_nodes, 128, 0, stream>>>(h, rows, cols, vals, out, n_edges);
    } else {
        fused_fallback<<<n_nodes, 128, 0, stream>>>(x, w, rows, cols, vals, out, n_edges);
    }
}

// Round 3
// 138.344 us; speedup vs baseline: 1.9556x; 1.1583x over previous
//
#include <hip/hip_runtime.h>
#include <hip/hip_bf16.h>

#define D 128           // D_IN == D_OUT == 128
#define GEMM_ROWS 32    // fallback tier only

typedef __bf16 bf16x8 __attribute__((ext_vector_type(8)));
typedef float  f32x4  __attribute__((ext_vector_type(4)));
typedef unsigned int u32x4 __attribute__((ext_vector_type(4)));

// ---------------------------------------------------------------------------
// Pre-kernel A: wT[n][k] = bf16(w[k][n]).  16384 elements, trivial.
// ---------------------------------------------------------------------------
__global__ void transpose_w(const float* __restrict__ w, unsigned short* __restrict__ wT) {
    int idx = blockIdx.x * 256 + threadIdx.x;      // coalesced read of w
    float v = w[idx];
    int k = idx >> 7, c = idx & 127;
    wT[c * D + k] = __builtin_bit_cast(unsigned short, (__bf16)v);
}

// ---------------------------------------------------------------------------
// Pre-kernel B: CSR row_ptr from sorted COO rows.
// ---------------------------------------------------------------------------
__global__ void build_row_ptr(const int* __restrict__ rows, int* __restrict__ row_ptr,
                              int n_edges, int n_nodes) {
    int e = blockIdx.x * 256 + threadIdx.x;
    if (e >= n_edges) return;
    int r    = rows[e];
    int prev = (e == 0) ? -1 : rows[e - 1];
    for (int rr = prev + 1; rr <= r; ++rr) row_ptr[rr] = e;
    if (e == n_edges - 1)
        for (int rr = r + 1; rr <= n_nodes; ++rr) row_ptr[rr] = n_edges;
}

// ---------------------------------------------------------------------------
// GEMM: h(bf16) = x @ w. Wave tile = 64 rows x 32 cols so the 8 B-frags
// (2 col-tiles x 4 k-chunks, 32 VGPRs) are loaded ONCE and held in registers
// — R2's per-iteration B reloads serialized the MFMA chain. Block = 4 waves
// covering 128 cols. 782 blocks (~3/CU) for latency hiding.
// ---------------------------------------------------------------------------
__device__ inline bf16x8 load_a_frag(const float* __restrict__ x, int r, int koff, int n) {
    float4 v0 = make_float4(0.f, 0.f, 0.f, 0.f), v1 = v0;
    if (r < n) {
        const float4* p = (const float4*)(x + (size_t)r * D + koff);
        v0 = p[0]; v1 = p[1];
    }
    bf16x8 a;
    a[0] = (__bf16)v0.x; a[1] = (__bf16)v0.y; a[2] = (__bf16)v0.z; a[3] = (__bf16)v0.w;
    a[4] = (__bf16)v1.x; a[5] = (__bf16)v1.y; a[6] = (__bf16)v1.z; a[7] = (__bf16)v1.w;
    return a;
}

__global__ __launch_bounds__(256) void gemm_mfma2(const float* __restrict__ x,
                                                  const unsigned short* __restrict__ wT,
                                                  unsigned short* __restrict__ h, int n) {
    const int wave = threadIdx.x >> 6;
    const int lane = threadIdx.x & 63;
    const int m16  = lane & 15;
    const int q    = lane >> 4;

    const int row0 = blockIdx.x * 64;
    const int col0 = wave * 32;

    // hoist all B fragments: t in {0,1} col-tiles, s in 0..3 k-chunks
    const u32x4* wTv = (const u32x4*)wT;
    bf16x8 bfr[2][4];
#pragma unroll
    for (int t = 0; t < 2; ++t)
#pragma unroll
        for (int s = 0; s < 4; ++s) {
            int ncol = col0 + 16 * t + m16;
            int koff = 32 * s + q * 8;
            bfr[t][s] = __builtin_bit_cast(bf16x8, wTv[(ncol * D + koff) >> 3]);
        }

    f32x4 acc[4][2];   // [row-slab][col-tile]
#pragma unroll
    for (int sl = 0; sl < 4; ++sl)
#pragma unroll
        for (int t = 0; t < 2; ++t) acc[sl][t] = (f32x4)0.f;

#pragma unroll
    for (int sl = 0; sl < 4; ++sl) {
#pragma unroll
        for (int s = 0; s < 4; ++s) {
            bf16x8 a = load_a_frag(x, row0 + sl * 16 + m16, 32 * s + q * 8, n);
            acc[sl][0] = __builtin_amdgcn_mfma_f32_16x16x32_bf16(a, bfr[0][s], acc[sl][0], 0, 0, 0);
            acc[sl][1] = __builtin_amdgcn_mfma_f32_16x16x32_bf16(a, bfr[1][s], acc[sl][1], 0, 0, 0);
        }
    }

    // D layout: col = lane&15, row = q*4 + i   [m89-verified]
#pragma unroll
    for (int sl = 0; sl < 4; ++sl)
#pragma unroll
        for (int t = 0; t < 2; ++t) {
            int col = col0 + 16 * t + m16;
#pragma unroll
            for (int i = 0; i < 4; ++i) {
                int row = row0 + sl * 16 + q * 4 + i;
                if (row < n)
                    h[(size_t)row * D + col] =
                        __builtin_bit_cast(unsigned short, (__bf16)acc[sl][t][i]);
            }
        }
}

// ---------------------------------------------------------------------------
// SpMM on bf16 h: one wave per row. bf16 row = 256B = 16 lanes x dwordx4, so
// 4 edge-chains per wave (+1-ahead prefetch) = up to 8 outstanding gathers.
// Unpack bf16 pairs with shift/mask, fp32 accumulate, ReLU fused.
// ---------------------------------------------------------------------------
__global__ __launch_bounds__(256) void spmm_bf16(const unsigned short* __restrict__ h,
                                                 const int* __restrict__ row_ptr,
                                                 const int* __restrict__ cols,
                                                 const float* __restrict__ vals,
                                                 float* __restrict__ out, int n) {
    const int wave = threadIdx.x >> 6;
    const int lane = threadIdx.x & 63;
    const int r = blockIdx.x * 4 + wave;
    if (r >= n) return;

    const int start = row_ptr[r];
    const int end   = row_ptr[r + 1];
    const int chain = lane >> 4;    // 4 edge chains
    const int l4    = lane & 15;    // 16B slot: dims [l4*8, l4*8+8)

    const u32x4* h4 = (const u32x4*)h;   // 16B = 8 bf16
    float acc[8];
#pragma unroll
    for (int j = 0; j < 8; ++j) acc[j] = 0.f;

    int e = start + chain;
    int c = 0; float v = 0.f;
    if (e < end) { c = cols[e]; v = vals[e]; }
    while (e < end) {
        int en = e + 4; int cn = 0; float vn = 0.f;
        if (en < end) { cn = cols[en]; vn = vals[en]; }    // overlaps gather
        u32x4 hv = h4[(size_t)c * (D / 8) + l4];
#pragma unroll
        for (int j = 0; j < 4; ++j) {
            unsigned int u = hv[j];
            float lo = __builtin_bit_cast(float, u << 16);
            float hi = __builtin_bit_cast(float, u & 0xFFFF0000u);
            acc[2 * j]     = fmaf(v, lo, acc[2 * j]);
            acc[2 * j + 1] = fmaf(v, hi, acc[2 * j + 1]);
        }
        c = cn; v = vn; e = en;
    }

    // combine 4 chains (lanes differ in bits 4,5)
#pragma unroll
    for (int j = 0; j < 8; ++j) {
        acc[j] += __shfl_xor(acc[j], 16);
        acc[j] += __shfl_xor(acc[j], 32);
    }

    if (chain == 0) {
        float4 o0, o1;
        o0.x = fmaxf(acc[0], 0.f); o0.y = fmaxf(acc[1], 0.f);
        o0.z = fmaxf(acc[2], 0.f); o0.w = fmaxf(acc[3], 0.f);
        o1.x = fmaxf(acc[4], 0.f); o1.y = fmaxf(acc[5], 0.f);
        o1.z = fmaxf(acc[6], 0.f); o1.w = fmaxf(acc[7], 0.f);
        float4* op = (float4*)(out + (size_t)r * D + l4 * 8);
        op[0] = o0; op[1] = o1;
    }
}

// ============================ fallback tiers ===============================
__global__ __launch_bounds__(256) void gemm128(const float* __restrict__ x,
                                               const float* __restrict__ w,
                                               float* __restrict__ h, int n) {
    __shared__ float4 ws4[D * D / 4];
    __shared__ float  xs[GEMM_ROWS][D];
    const int tid  = threadIdx.x;
    const int row0 = blockIdx.x * GEMM_ROWS;
    const float4* w4 = (const float4*)w;
    for (int i = tid; i < D * D / 4; i += 256) ws4[i] = w4[i];
    float4* xs4 = (float4*)&xs[0][0];
    const float4* x4 = (const float4*)x;
    for (int i = tid; i < GEMM_ROWS * D / 4; i += 256) {
        int row = row0 + (i >> 5);
        float4 v = make_float4(0.f, 0.f, 0.f, 0.f);
        if (row < n) v = x4[(size_t)row0 * (D / 4) + i];
        xs4[i] = v;
    }
    __syncthreads();
    const int tx = tid & 31, ty = tid >> 5;
    float4 acc[4];
#pragma unroll
    for (int i = 0; i < 4; ++i) acc[i] = make_float4(0.f, 0.f, 0.f, 0.f);
#pragma unroll 8
    for (int k = 0; k < D; ++k) {
        float4 wv = ws4[k * (D / 4) + tx];
#pragma unroll
        for (int i = 0; i < 4; ++i) {
            float xv = xs[ty * 4 + i][k];
            acc[i].x = fmaf(xv, wv.x, acc[i].x);
            acc[i].y = fmaf(xv, wv.y, acc[i].y);
            acc[i].z = fmaf(xv, wv.z, acc[i].z);
            acc[i].w = fmaf(xv, wv.w, acc[i].w);
        }
    }
#pragma unroll
    for (int i = 0; i < 4; ++i) {
        int row = row0 + ty * 4 + i;
        if (row < n) ((float4*)(h + (size_t)row * D))[tx] = acc[i];
    }
}

__global__ __launch_bounds__(128) void spmm_row(const float* __restrict__ h,
                                                const int* __restrict__ rows,
                                                const int* __restrict__ cols,
                                                const float* __restrict__ vals,
                                                float* __restrict__ out, int n_edges) {
    const int r = blockIdx.x, d = threadIdx.x;
    int lo = 0, hi = n_edges;
    while (lo < hi) { int m = (lo + hi) >> 1; if (rows[m] < r) lo = m + 1; else hi = m; }
    const int start = lo;
    hi = n_edges;
    while (lo < hi) { int m = (lo + hi) >> 1; if (rows[m] <= r) lo = m + 1; else hi = m; }
    const int end = lo;
    float acc = 0.f;
    for (int e = start; e < end; ++e)
        acc = fmaf(vals[e], h[(size_t)cols[e] * D + d], acc);
    out[(size_t)r * D + d] = fmaxf(acc, 0.f);
}

__global__ __launch_bounds__(128) void fused_fallback(
        const float* __restrict__ x, const float* __restrict__ w,
        const int* __restrict__ rows, const int* __restrict__ cols,
        const float* __restrict__ vals, float* __restrict__ out, int n_edges) {
    const int r = blockIdx.x, d = threadIdx.x;
    int lo = 0, hi = n_edges;
    while (lo < hi) { int m = (lo + hi) >> 1; if (rows[m] < r) lo = m + 1; else hi = m; }
    const int start = lo;
    hi = n_edges;
    while (lo < hi) { int m = (lo + hi) >> 1; if (rows[m] <= r) lo = m + 1; else hi = m; }
    const int end = lo;
    float acc = 0.f;
    for (int e = start; e < end; ++e) {
        int c = cols[e]; float v = vals[e];
        float hcd = 0.f;
        for (int k = 0; k < D; ++k)
            hcd = fmaf(x[(size_t)c * D + k], w[(size_t)k * D + d], hcd);
        acc = fmaf(v, hcd, acc);
    }
    out[(size_t)r * D + d] = fmaxf(acc, 0.f);
}

// ===========================================================================
extern "C" void kernel_launch(void* const* d_in, const int* in_sizes, int n_in,
                              void* d_out, int out_size, void* d_ws, size_t ws_size,
                              hipStream_t stream) {
    const float* x    = (const float*)d_in[0];
    const float* w    = (const float*)d_in[1];
    const int*   rows = (const int*)d_in[2];
    const int*   cols = (const int*)d_in[3];
    const float* vals = (const float*)d_in[4];
    float* out = (float*)d_out;

    const int n_nodes = in_sizes[0] / D;   // 50000
    const int n_edges = in_sizes[2];       // 800000

    // tier-1 layout: h_bf16 | wT | row_ptr
    const size_t hb_bytes = (size_t)n_nodes * D * sizeof(unsigned short);  // 12.8 MB
    const size_t wT_off   = (hb_bytes + 15) & ~(size_t)15;
    const size_t rp_off   = wT_off + (size_t)D * D * sizeof(unsigned short);
    const size_t need     = rp_off + (size_t)(n_nodes + 1) * sizeof(int);
    const size_t hf_bytes = (size_t)n_nodes * D * sizeof(float);           // 25.6 MB

    if (ws_size >= need) {
        unsigned short* h  = (unsigned short*)d_ws;
        unsigned short* wT = (unsigned short*)((char*)d_ws + wT_off);
        int*            rp = (int*)((char*)d_ws + rp_off);

        transpose_w<<<(D * D) / 256, 256, 0, stream>>>(w, wT);
        build_row_ptr<<<(n_edges + 255) / 256, 256, 0, stream>>>(rows, rp, n_edges, n_nodes);
        gemm_mfma2<<<(n_nodes + 63) / 64, 256, 0, stream>>>(x, wT, h, n_nodes);
        spmm_bf16<<<(n_nodes + 3) / 4, 256, 0, stream>>>(h, rp, cols, vals, out, n_nodes);
    } else if (ws_size >= hf_bytes) {
        float* h = (float*)d_ws;
        gemm128<<<(n_nodes + GEMM_ROWS - 1) / GEMM_ROWS, 256, 0, stream>>>(x, w, h, n_nodes);
        spmm_row<<<n_nodes, 128, 0, stream>>>(h, rows, cols, vals, out, n_edges);
    } else {
        fused_fallback<<<n_nodes, 128, 0, stream>>>(x, w, rows, cols, vals, out, n_edges);
    }
}

// Round 4
// 133.756 us; speedup vs baseline: 2.0227x; 1.0343x over previous
//
#include <hip/hip_runtime.h>
#include <hip/hip_bf16.h>

#define D 128           // D_IN == D_OUT == 128
#define GEMM_ROWS 32    // fallback tier only

typedef __bf16 bf16x8 __attribute__((ext_vector_type(8)));
typedef float  f32x4  __attribute__((ext_vector_type(4)));
typedef unsigned int u32x4 __attribute__((ext_vector_type(4)));

__device__ inline unsigned int pk_bf16(float lo, float hi) {
    unsigned short a = __builtin_bit_cast(unsigned short, (__bf16)lo);
    unsigned short b = __builtin_bit_cast(unsigned short, (__bf16)hi);
    return ((unsigned int)b << 16) | (unsigned int)a;
}

// ---------------------------------------------------------------------------
// Merged preprocess (one launch):
//   blocks [0, xb_blocks)            : xb = bf16(x), rows padded to n_pad w/ 0
//   blocks [xb_blocks, +w_blocks)    : wT[n][k] = bf16(w[k][n])
//   blocks [xb_blocks+w_blocks, ...) : CSR row_ptr from sorted COO rows
// ---------------------------------------------------------------------------
__global__ __launch_bounds__(256) void preprocess(
        const float* __restrict__ x, const float* __restrict__ w,
        const int* __restrict__ rows,
        unsigned short* __restrict__ xb, unsigned short* __restrict__ wT,
        int* __restrict__ rp,
        int n_nodes, int n_pad, int n_edges, int xb_blocks, int w_blocks) {
    const int b = blockIdx.x;
    if (b < xb_blocks) {
        // one thread = 8 consecutive elements (16 chunks per row of 128)
        int t = b * 256 + threadIdx.x;
        int row = t >> 4, chunk = t & 15;
        if (row >= n_pad) return;
        u32x4 o = (u32x4)0u;
        if (row < n_nodes) {
            const float4* p = (const float4*)(x + (size_t)row * D + chunk * 8);
            float4 v0 = p[0], v1 = p[1];
            o[0] = pk_bf16(v0.x, v0.y); o[1] = pk_bf16(v0.z, v0.w);
            o[2] = pk_bf16(v1.x, v1.y); o[3] = pk_bf16(v1.z, v1.w);
        }
        ((u32x4*)xb)[t] = o;
    } else if (b < xb_blocks + w_blocks) {
        int t = (b - xb_blocks) * 256 + threadIdx.x;   // 8 elems each, 2048 thr
#pragma unroll
        for (int j = 0; j < 8; ++j) {
            int idx = t * 8 + j;
            float v = w[idx];                          // coalesced read
            int k = idx >> 7, c = idx & 127;
            wT[c * D + k] = __builtin_bit_cast(unsigned short, (__bf16)v);
        }
    } else {
        int e = (b - xb_blocks - w_blocks) * 256 + threadIdx.x;
        if (e >= n_edges) return;
        int r    = rows[e];
        int prev = (e == 0) ? -1 : rows[e - 1];
        for (int rr = prev + 1; rr <= r; ++rr) rp[rr] = e;
        if (e == n_edges - 1)
            for (int rr = r + 1; rr <= n_nodes; ++rr) rp[rr] = n_edges;
    }
}

// ---------------------------------------------------------------------------
// GEMM v3: h(bf16) = xb(bf16) @ w.  A-frag = ONE 16B load from padded xb
// (no fp32 staging -> no spills, no converts, no bounds guards in the loop).
// Wave tile 64 rows x 32 cols; 8 B-frags hoisted in registers for the whole
// kernel. VGPR budget ~150: bfr 32 + acc 32 + A-in-flight <=64 + addr.
// ---------------------------------------------------------------------------
__global__ __launch_bounds__(256) void gemm_v3(const unsigned short* __restrict__ xb,
                                               const unsigned short* __restrict__ wT,
                                               unsigned short* __restrict__ h,
                                               int n_pad) {
    const int wave = threadIdx.x >> 6;
    const int lane = threadIdx.x & 63;
    const int m16  = lane & 15;
    const int q    = lane >> 4;

    const int row0 = blockIdx.x * 64;
    const int col0 = wave * 32;

    const u32x4* xbv = (const u32x4*)xb;
    const u32x4* wTv = (const u32x4*)wT;

    // hoist all B fragments (L2-resident wT)
    bf16x8 bfr[2][4];
#pragma unroll
    for (int t = 0; t < 2; ++t)
#pragma unroll
        for (int s = 0; s < 4; ++s) {
            int ncol = col0 + 16 * t + m16;
            int koff = 32 * s + q * 8;
            bfr[t][s] = __builtin_bit_cast(bf16x8, wTv[(ncol * D + koff) >> 3]);
        }

    f32x4 acc[4][2];
#pragma unroll
    for (int sl = 0; sl < 4; ++sl)
#pragma unroll
        for (int t = 0; t < 2; ++t) acc[sl][t] = (f32x4)0.f;

#pragma unroll
    for (int sl = 0; sl < 4; ++sl) {
        const size_t rbase = (size_t)(row0 + sl * 16 + m16) * D;
#pragma unroll
        for (int s = 0; s < 4; ++s) {
            bf16x8 a = __builtin_bit_cast(bf16x8, xbv[(rbase + 32 * s + q * 8) >> 3]);
            acc[sl][0] = __builtin_amdgcn_mfma_f32_16x16x32_bf16(a, bfr[0][s], acc[sl][0], 0, 0, 0);
            acc[sl][1] = __builtin_amdgcn_mfma_f32_16x16x32_bf16(a, bfr[1][s], acc[sl][1], 0, 0, 0);
        }
    }

    // D layout: col = lane&15, row = q*4 + i   [m89-verified]; h is padded.
#pragma unroll
    for (int sl = 0; sl < 4; ++sl)
#pragma unroll
        for (int t = 0; t < 2; ++t) {
            int col = col0 + 16 * t + m16;
#pragma unroll
            for (int i = 0; i < 4; ++i) {
                int row = row0 + sl * 16 + q * 4 + i;
                h[(size_t)row * D + col] =
                    __builtin_bit_cast(unsigned short, (__bf16)acc[sl][t][i]);
            }
        }
}

// ---------------------------------------------------------------------------
// SpMM on bf16 h (unchanged from R3): one wave per row, 4 edge-chains of
// 16 lanes x 16B, 1-ahead col/val prefetch, fp32 accumulate, fused ReLU.
// ---------------------------------------------------------------------------
__global__ __launch_bounds__(256) void spmm_bf16(const unsigned short* __restrict__ h,
                                                 const int* __restrict__ row_ptr,
                                                 const int* __restrict__ cols,
                                                 const float* __restrict__ vals,
                                                 float* __restrict__ out, int n) {
    const int wave = threadIdx.x >> 6;
    const int lane = threadIdx.x & 63;
    const int r = blockIdx.x * 4 + wave;
    if (r >= n) return;

    const int start = row_ptr[r];
    const int end   = row_ptr[r + 1];
    const int chain = lane >> 4;
    const int l4    = lane & 15;

    const u32x4* h4 = (const u32x4*)h;
    float acc[8];
#pragma unroll
    for (int j = 0; j < 8; ++j) acc[j] = 0.f;

    int e = start + chain;
    int c = 0; float v = 0.f;
    if (e < end) { c = cols[e]; v = vals[e]; }
    while (e < end) {
        int en = e + 4; int cn = 0; float vn = 0.f;
        if (en < end) { cn = cols[en]; vn = vals[en]; }
        u32x4 hv = h4[(size_t)c * (D / 8) + l4];
#pragma unroll
        for (int j = 0; j < 4; ++j) {
            unsigned int u = hv[j];
            float lo = __builtin_bit_cast(float, u << 16);
            float hi = __builtin_bit_cast(float, u & 0xFFFF0000u);
            acc[2 * j]     = fmaf(v, lo, acc[2 * j]);
            acc[2 * j + 1] = fmaf(v, hi, acc[2 * j + 1]);
        }
        c = cn; v = vn; e = en;
    }

#pragma unroll
    for (int j = 0; j < 8; ++j) {
        acc[j] += __shfl_xor(acc[j], 16);
        acc[j] += __shfl_xor(acc[j], 32);
    }

    if (chain == 0) {
        float4 o0, o1;
        o0.x = fmaxf(acc[0], 0.f); o0.y = fmaxf(acc[1], 0.f);
        o0.z = fmaxf(acc[2], 0.f); o0.w = fmaxf(acc[3], 0.f);
        o1.x = fmaxf(acc[4], 0.f); o1.y = fmaxf(acc[5], 0.f);
        o1.z = fmaxf(acc[6], 0.f); o1.w = fmaxf(acc[7], 0.f);
        float4* op = (float4*)(out + (size_t)r * D + l4 * 8);
        op[0] = o0; op[1] = o1;
    }
}

// ============================ fallback tiers ===============================
__global__ __launch_bounds__(256) void gemm128(const float* __restrict__ x,
                                               const float* __restrict__ w,
                                               float* __restrict__ h, int n) {
    __shared__ float4 ws4[D * D / 4];
    __shared__ float  xs[GEMM_ROWS][D];
    const int tid  = threadIdx.x;
    const int row0 = blockIdx.x * GEMM_ROWS;
    const float4* w4 = (const float4*)w;
    for (int i = tid; i < D * D / 4; i += 256) ws4[i] = w4[i];
    float4* xs4 = (float4*)&xs[0][0];
    const float4* x4 = (const float4*)x;
    for (int i = tid; i < GEMM_ROWS * D / 4; i += 256) {
        int row = row0 + (i >> 5);
        float4 v = make_float4(0.f, 0.f, 0.f, 0.f);
        if (row < n) v = x4[(size_t)row0 * (D / 4) + i];
        xs4[i] = v;
    }
    __syncthreads();
    const int tx = tid & 31, ty = tid >> 5;
    float4 acc[4];
#pragma unroll
    for (int i = 0; i < 4; ++i) acc[i] = make_float4(0.f, 0.f, 0.f, 0.f);
#pragma unroll 8
    for (int k = 0; k < D; ++k) {
        float4 wv = ws4[k * (D / 4) + tx];
#pragma unroll
        for (int i = 0; i < 4; ++i) {
            float xv = xs[ty * 4 + i][k];
            acc[i].x = fmaf(xv, wv.x, acc[i].x);
            acc[i].y = fmaf(xv, wv.y, acc[i].y);
            acc[i].z = fmaf(xv, wv.z, acc[i].z);
            acc[i].w = fmaf(xv, wv.w, acc[i].w);
        }
    }
#pragma unroll
    for (int i = 0; i < 4; ++i) {
        int row = row0 + ty * 4 + i;
        if (row < n) ((float4*)(h + (size_t)row * D))[tx] = acc[i];
    }
}

__global__ __launch_bounds__(128) void spmm_row(const float* __restrict__ h,
                                                const int* __restrict__ rows,
                                                const int* __restrict__ cols,
                                                const float* __restrict__ vals,
                                                float* __restrict__ out, int n_edges) {
    const int r = blockIdx.x, d = threadIdx.x;
    int lo = 0, hi = n_edges;
    while (lo < hi) { int m = (lo + hi) >> 1; if (rows[m] < r) lo = m + 1; else hi = m; }
    const int start = lo;
    hi = n_edges;
    while (lo < hi) { int m = (lo + hi) >> 1; if (rows[m] <= r) lo = m + 1; else hi = m; }
    const int end = lo;
    float acc = 0.f;
    for (int e = start; e < end; ++e)
        acc = fmaf(vals[e], h[(size_t)cols[e] * D + d], acc);
    out[(size_t)r * D + d] = fmaxf(acc, 0.f);
}

__global__ __launch_bounds__(128) void fused_fallback(
        const float* __restrict__ x, const float* __restrict__ w,
        const int* __restrict__ rows, const int* __restrict__ cols,
        const float* __restrict__ vals, float* __restrict__ out, int n_edges) {
    const int r = blockIdx.x, d = threadIdx.x;
    int lo = 0, hi = n_edges;
    while (lo < hi) { int m = (lo + hi) >> 1; if (rows[m] < r) lo = m + 1; else hi = m; }
    const int start = lo;
    hi = n_edges;
    while (lo < hi) { int m = (lo + hi) >> 1; if (rows[m] <= r) lo = m + 1; else hi = m; }
    const int end = lo;
    float acc = 0.f;
    for (int e = start; e < end; ++e) {
        int c = cols[e]; float v = vals[e];
        float hcd = 0.f;
        for (int k = 0; k < D; ++k)
            hcd = fmaf(x[(size_t)c * D + k], w[(size_t)k * D + d], hcd);
        acc = fmaf(v, hcd, acc);
    }
    out[(size_t)r * D + d] = fmaxf(acc, 0.f);
}

// ===========================================================================
extern "C" void kernel_launch(void* const* d_in, const int* in_sizes, int n_in,
                              void* d_out, int out_size, void* d_ws, size_t ws_size,
                              hipStream_t stream) {
    const float* x    = (const float*)d_in[0];
    const float* w    = (const float*)d_in[1];
    const int*   rows = (const int*)d_in[2];
    const int*   cols = (const int*)d_in[3];
    const float* vals = (const float*)d_in[4];
    float* out = (float*)d_out;

    const int n_nodes = in_sizes[0] / D;              // 50000
    const int n_edges = in_sizes[2];                  // 800000
    const int n_pad   = (n_nodes + 63) & ~63;         // 50048

    // tier-1 ws layout: xb | h | wT | row_ptr   (all 16B-aligned)
    const size_t xb_bytes = (size_t)n_pad * D * sizeof(unsigned short);
    const size_t h_off    = xb_bytes;
    const size_t wT_off   = h_off + xb_bytes;
    const size_t rp_off   = wT_off + (size_t)D * D * sizeof(unsigned short);
    const size_t need     = rp_off + (size_t)(n_nodes + 1) * sizeof(int);
    const size_t hf_bytes = (size_t)n_nodes * D * sizeof(float);

    if (ws_size >= need) {
        unsigned short* xb = (unsigned short*)d_ws;
        unsigned short* h  = (unsigned short*)((char*)d_ws + h_off);
        unsigned short* wT = (unsigned short*)((char*)d_ws + wT_off);
        int*            rp = (int*)((char*)d_ws + rp_off);

        const int xb_blocks = (n_pad * (D / 8)) / 256;           // 3128
        const int w_blocks  = (D * D) / (256 * 8);               // 8
        const int rp_blocks = (n_edges + 255) / 256;             // 3125
        preprocess<<<xb_blocks + w_blocks + rp_blocks, 256, 0, stream>>>(
            x, w, rows, xb, wT, rp, n_nodes, n_pad, n_edges, xb_blocks, w_blocks);

        gemm_v3<<<n_pad / 64, 256, 0, stream>>>(xb, wT, h, n_pad);
        spmm_bf16<<<(n_nodes + 3) / 4, 256, 0, stream>>>(h, rp, cols, vals, out, n_nodes);
    } else if (ws_size >= hf_bytes) {
        float* hf = (float*)d_ws;
        gemm128<<<(n_nodes + GEMM_ROWS - 1) / GEMM_ROWS, 256, 0, stream>>>(x, w, hf, n_nodes);
        spmm_row<<<n_nodes, 128, 0, stream>>>(hf, rows, cols, vals, out, n_edges);
    } else {
        fused_fallback<<<n_nodes, 128, 0, stream>>>(x, w, rows, cols, vals, out, n_edges);
    }
}

// Round 5
// 131.405 us; speedup vs baseline: 2.0589x; 1.0179x over previous
//
#include <hip/hip_runtime.h>
#include <hip/hip_bf16.h>

#define D 128           // D_IN == D_OUT == 128
#define GEMM_ROWS 32    // fallback tier only

typedef __bf16 bf16x8 __attribute__((ext_vector_type(8)));
typedef float  f32x4  __attribute__((ext_vector_type(4)));
typedef unsigned int u32x4 __attribute__((ext_vector_type(4)));

// ---------------------------------------------------------------------------
// K1: fused GEMM + row_ptr (single launch, no intermediate arrays).
//   blocks [0, gemm_blocks)  : h(bf16) = x @ w
//       A: fp32 from x, cvt in-register per 16-row slab (unroll 1 -> ~100 VGPR)
//       B: 8 frags direct from fp32 w (stride-512B, L2-hot after 1st block)
//   blocks [gemm_blocks, ...): CSR row_ptr from sorted COO rows
// ---------------------------------------------------------------------------
__device__ inline bf16x8 cvt_a8(const float* __restrict__ p) {
    float4 v0 = ((const float4*)p)[0], v1 = ((const float4*)p)[1];
    bf16x8 a;
    a[0] = (__bf16)v0.x; a[1] = (__bf16)v0.y; a[2] = (__bf16)v0.z; a[3] = (__bf16)v0.w;
    a[4] = (__bf16)v1.x; a[5] = (__bf16)v1.y; a[6] = (__bf16)v1.z; a[7] = (__bf16)v1.w;
    return a;
}

__global__ __launch_bounds__(256) void fused_gemm_rp(
        const float* __restrict__ x, const float* __restrict__ w,
        const int* __restrict__ rows,
        unsigned short* __restrict__ h, int* __restrict__ rp,
        int n_nodes, int n_edges, int gemm_blocks) {
    const int b = blockIdx.x;

    if (b >= gemm_blocks) {           // ---- row_ptr builder blocks ----
        int e = (b - gemm_blocks) * 256 + threadIdx.x;
        if (e >= n_edges) return;
        int r    = rows[e];
        int prev = (e == 0) ? -1 : rows[e - 1];
        for (int rr = prev + 1; rr <= r; ++rr) rp[rr] = e;
        if (e == n_edges - 1)
            for (int rr = r + 1; rr <= n_nodes; ++rr) rp[rr] = n_edges;
        return;
    }

    // ---- GEMM blocks: 64 rows x 128 cols per block, wave = 64r x 32c ----
    const int wave = threadIdx.x >> 6;
    const int lane = threadIdx.x & 63;
    const int m16  = lane & 15;
    const int q    = lane >> 4;

    const int row0 = b * 64;
    const int col0 = wave * 32;

    // B fragments straight from w: bfr[t][s][j] = w[k=32s+8q+j][n=col0+16t+m16]
    bf16x8 bfr[2][4];
#pragma unroll
    for (int t = 0; t < 2; ++t)
#pragma unroll
        for (int s = 0; s < 4; ++s) {
            const float* wp = w + (size_t)(32 * s + q * 8) * D + col0 + 16 * t + m16;
#pragma unroll
            for (int j = 0; j < 8; ++j)
                bfr[t][s][j] = (__bf16)wp[(size_t)j * D];
        }

#pragma unroll 1                       // keep one 16-row slab live at a time
    for (int sl = 0; sl < 4; ++sl) {
        const int r = row0 + sl * 16 + m16;
        const float* xp = x + (size_t)r * D + q * 8;

        bf16x8 a[4];
        if (r < n_nodes) {
#pragma unroll
            for (int s = 0; s < 4; ++s) a[s] = cvt_a8(xp + 32 * s);
        } else {
#pragma unroll
            for (int s = 0; s < 4; ++s)
#pragma unroll
                for (int j = 0; j < 8; ++j) a[s][j] = (__bf16)0.f;
        }

        f32x4 acc0 = (f32x4)0.f, acc1 = (f32x4)0.f;
#pragma unroll
        for (int s = 0; s < 4; ++s) {
            acc0 = __builtin_amdgcn_mfma_f32_16x16x32_bf16(a[s], bfr[0][s], acc0, 0, 0, 0);
            acc1 = __builtin_amdgcn_mfma_f32_16x16x32_bf16(a[s], bfr[1][s], acc1, 0, 0, 0);
        }

        // D layout: col = lane&15, row = q*4+i [m89]; h rows padded -> no guard
#pragma unroll
        for (int i = 0; i < 4; ++i) {
            int row = row0 + sl * 16 + q * 4 + i;
            h[(size_t)row * D + col0 + m16]      = __builtin_bit_cast(unsigned short, (__bf16)acc0[i]);
            h[(size_t)row * D + col0 + 16 + m16] = __builtin_bit_cast(unsigned short, (__bf16)acc1[i]);
        }
    }
}

// ---------------------------------------------------------------------------
// K2 (UNCHANGED control): SpMM on bf16 h. One wave per row, 4 edge-chains of
// 16 lanes x 16B, 1-ahead col/val prefetch, fp32 accumulate, fused ReLU.
// ---------------------------------------------------------------------------
__global__ __launch_bounds__(256) void spmm_bf16(const unsigned short* __restrict__ h,
                                                 const int* __restrict__ row_ptr,
                                                 const int* __restrict__ cols,
                                                 const float* __restrict__ vals,
                                                 float* __restrict__ out, int n) {
    const int wave = threadIdx.x >> 6;
    const int lane = threadIdx.x & 63;
    const int r = blockIdx.x * 4 + wave;
    if (r >= n) return;

    const int start = row_ptr[r];
    const int end   = row_ptr[r + 1];
    const int chain = lane >> 4;
    const int l4    = lane & 15;

    const u32x4* h4 = (const u32x4*)h;
    float acc[8];
#pragma unroll
    for (int j = 0; j < 8; ++j) acc[j] = 0.f;

    int e = start + chain;
    int c = 0; float v = 0.f;
    if (e < end) { c = cols[e]; v = vals[e]; }
    while (e < end) {
        int en = e + 4; int cn = 0; float vn = 0.f;
        if (en < end) { cn = cols[en]; vn = vals[en]; }
        u32x4 hv = h4[(size_t)c * (D / 8) + l4];
#pragma unroll
        for (int j = 0; j < 4; ++j) {
            unsigned int u = hv[j];
            float lo = __builtin_bit_cast(float, u << 16);
            float hi = __builtin_bit_cast(float, u & 0xFFFF0000u);
            acc[2 * j]     = fmaf(v, lo, acc[2 * j]);
            acc[2 * j + 1] = fmaf(v, hi, acc[2 * j + 1]);
        }
        c = cn; v = vn; e = en;
    }

#pragma unroll
    for (int j = 0; j < 8; ++j) {
        acc[j] += __shfl_xor(acc[j], 16);
        acc[j] += __shfl_xor(acc[j], 32);
    }

    if (chain == 0) {
        float4 o0, o1;
        o0.x = fmaxf(acc[0], 0.f); o0.y = fmaxf(acc[1], 0.f);
        o0.z = fmaxf(acc[2], 0.f); o0.w = fmaxf(acc[3], 0.f);
        o1.x = fmaxf(acc[4], 0.f); o1.y = fmaxf(acc[5], 0.f);
        o1.z = fmaxf(acc[6], 0.f); o1.w = fmaxf(acc[7], 0.f);
        float4* op = (float4*)(out + (size_t)r * D + l4 * 8);
        op[0] = o0; op[1] = o1;
    }
}

// ============================ fallback tiers ===============================
__global__ __launch_bounds__(256) void gemm128(const float* __restrict__ x,
                                               const float* __restrict__ w,
                                               float* __restrict__ h, int n) {
    __shared__ float4 ws4[D * D / 4];
    __shared__ float  xs[GEMM_ROWS][D];
    const int tid  = threadIdx.x;
    const int row0 = blockIdx.x * GEMM_ROWS;
    const float4* w4 = (const float4*)w;
    for (int i = tid; i < D * D / 4; i += 256) ws4[i] = w4[i];
    float4* xs4 = (float4*)&xs[0][0];
    const float4* x4 = (const float4*)x;
    for (int i = tid; i < GEMM_ROWS * D / 4; i += 256) {
        int row = row0 + (i >> 5);
        float4 v = make_float4(0.f, 0.f, 0.f, 0.f);
        if (row < n) v = x4[(size_t)row0 * (D / 4) + i];
        xs4[i] = v;
    }
    __syncthreads();
    const int tx = tid & 31, ty = tid >> 5;
    float4 acc[4];
#pragma unroll
    for (int i = 0; i < 4; ++i) acc[i] = make_float4(0.f, 0.f, 0.f, 0.f);
#pragma unroll 8
    for (int k = 0; k < D; ++k) {
        float4 wv = ws4[k * (D / 4) + tx];
#pragma unroll
        for (int i = 0; i < 4; ++i) {
            float xv = xs[ty * 4 + i][k];
            acc[i].x = fmaf(xv, wv.x, acc[i].x);
            acc[i].y = fmaf(xv, wv.y, acc[i].y);
            acc[i].z = fmaf(xv, wv.z, acc[i].z);
            acc[i].w = fmaf(xv, wv.w, acc[i].w);
        }
    }
#pragma unroll
    for (int i = 0; i < 4; ++i) {
        int row = row0 + ty * 4 + i;
        if (row < n) ((float4*)(h + (size_t)row * D))[tx] = acc[i];
    }
}

__global__ __launch_bounds__(128) void spmm_row(const float* __restrict__ h,
                                                const int* __restrict__ rows,
                                                const int* __restrict__ cols,
                                                const float* __restrict__ vals,
                                                float* __restrict__ out, int n_edges) {
    const int r = blockIdx.x, d = threadIdx.x;
    int lo = 0, hi = n_edges;
    while (lo < hi) { int m = (lo + hi) >> 1; if (rows[m] < r) lo = m + 1; else hi = m; }
    const int start = lo;
    hi = n_edges;
    while (lo < hi) { int m = (lo + hi) >> 1; if (rows[m] <= r) lo = m + 1; else hi = m; }
    const int end = lo;
    float acc = 0.f;
    for (int e = start; e < end; ++e)
        acc = fmaf(vals[e], h[(size_t)cols[e] * D + d], acc);
    out[(size_t)r * D + d] = fmaxf(acc, 0.f);
}

__global__ __launch_bounds__(128) void fused_fallback(
        const float* __restrict__ x, const float* __restrict__ w,
        const int* __restrict__ rows, const int* __restrict__ cols,
        const float* __restrict__ vals, float* __restrict__ out, int n_edges) {
    const int r = blockIdx.x, d = threadIdx.x;
    int lo = 0, hi = n_edges;
    while (lo < hi) { int m = (lo + hi) >> 1; if (rows[m] < r) lo = m + 1; else hi = m; }
    const int start = lo;
    hi = n_edges;
    while (lo < hi) { int m = (lo + hi) >> 1; if (rows[m] <= r) lo = m + 1; else hi = m; }
    const int end = lo;
    float acc = 0.f;
    for (int e = start; e < end; ++e) {
        int c = cols[e]; float v = vals[e];
        float hcd = 0.f;
        for (int k = 0; k < D; ++k)
            hcd = fmaf(x[(size_t)c * D + k], w[(size_t)k * D + d], hcd);
        acc = fmaf(v, hcd, acc);
    }
    out[(size_t)r * D + d] = fmaxf(acc, 0.f);
}

// ===========================================================================
extern "C" void kernel_launch(void* const* d_in, const int* in_sizes, int n_in,
                              void* d_out, int out_size, void* d_ws, size_t ws_size,
                              hipStream_t stream) {
    const float* x    = (const float*)d_in[0];
    const float* w    = (const float*)d_in[1];
    const int*   rows = (const int*)d_in[2];
    const int*   cols = (const int*)d_in[3];
    const float* vals = (const float*)d_in[4];
    float* out = (float*)d_out;

    const int n_nodes = in_sizes[0] / D;              // 50000
    const int n_edges = in_sizes[2];                  // 800000
    const int n_pad   = (n_nodes + 63) & ~63;         // 50048

    // tier-1 ws layout: h(bf16, n_pad rows) | row_ptr
    const size_t h_bytes  = (size_t)n_pad * D * sizeof(unsigned short);  // 12.8 MB
    const size_t rp_off   = h_bytes;
    const size_t need     = rp_off + (size_t)(n_nodes + 1) * sizeof(int);
    const size_t hf_bytes = (size_t)n_nodes * D * sizeof(float);

    if (ws_size >= need) {
        unsigned short* h  = (unsigned short*)d_ws;
        int*            rp = (int*)((char*)d_ws + rp_off);

        const int gemm_blocks = n_pad / 64;                      // 782
        const int rp_blocks   = (n_edges + 255) / 256;           // 3125
        fused_gemm_rp<<<gemm_blocks + rp_blocks, 256, 0, stream>>>(
            x, w, rows, h, rp, n_nodes, n_edges, gemm_blocks);
        spmm_bf16<<<(n_nodes + 3) / 4, 256, 0, stream>>>(h, rp, cols, vals, out, n_nodes);
    } else if (ws_size >= hf_bytes) {
        float* hf = (float*)d_ws;
        gemm128<<<(n_nodes + GEMM_ROWS - 1) / GEMM_ROWS, 256, 0, stream>>>(x, w, hf, n_nodes);
        spmm_row<<<n_nodes, 128, 0, stream>>>(hf, rows, cols, vals, out, n_edges);
    } else {
        fused_fallback<<<n_nodes, 128, 0, stream>>>(x, w, rows, cols, vals, out, n_edges);
    }
}